// Round 4
// baseline (68309.650 us; speedup 1.0000x reference)
//
#include <hip/hip_runtime.h>

// GRU decoder B=64,T=512,IN=H=512,L=2. Persistent pipelined cooperative grid:
//   blocks [0,128)  = cell A (layer0 @ t),  blocks [128,256) = cell B (layer1 @ t-1)
// 256 blocks x 512 threads (8 waves, 2/SIMD). Block = 4 cols; wave = 4 cols x K-octant.
//
// Round-4 change: NO cache-invalidating fence in the loop. Only h-state is
// coherent (relaxed system-scope atomics -> global_load/store sc0 sc1, L3 =
// coherence point). Weights + x use normal cached loads and stay L1/L2-warm
// across all ticks (round 3 showed the per-tick agent fence forced every
// weight load to L3: 32 of the 38.6 us/tick).

#define NBLK 256
#define NTHR 512
#define Bsz  64
#define Tlen 512
#define Kd   512
#define Hd   512
#define KC   64
#define LP   67   // LDS pitch for x-staging

__device__ __forceinline__ float sigf(float v){ return 1.0f/(1.0f+__expf(-v)); }
__device__ __forceinline__ float tanhx(float v){
  float e=__expf(-2.0f*fabsf(v)); float t=(1.0f-e)/(1.0f+e); return v<0.0f?-t:t;
}
__device__ __forceinline__ unsigned umin2(unsigned a, unsigned b){ return a<b?a:b; }

// coherent h-state access: relaxed system-scope -> sc0 sc1, bypasses L1/L2,
// compiler tracks waitcnts (loads stay pipelined, no per-load drain).
__device__ __forceinline__ float ld_sys(const float* p){
  return __hip_atomic_load(const_cast<float*>(p), __ATOMIC_RELAXED, __HIP_MEMORY_SCOPE_SYSTEM);
}
__device__ __forceinline__ void st_sys(float* p, float v){
  __hip_atomic_store(p, v, __ATOMIC_RELAXED, __HIP_MEMORY_SCOPE_SYSTEM);
}
__device__ __forceinline__ unsigned ld_sys_u(const unsigned* p){
  return __hip_atomic_load(const_cast<unsigned*>(p), __ATOMIC_RELAXED, __HIP_MEMORY_SCOPE_SYSTEM);
}
__device__ __forceinline__ void st_sys_u(unsigned* p, unsigned v){
  __hip_atomic_store(p, v, __ATOMIC_RELAXED, __HIP_MEMORY_SCOPE_SYSTEM);
}

// Grid barrier, per-block monotonic slots (no RMW contention).
// Release: __syncthreads (compiler drains vmcnt before s_barrier) -> all
// block stores (incl. sc0sc1 h-stores) committed; then relaxed slot store.
// Acquire: wave0 polls all 256 slots coherently; workgroup acquire fence
// only (compiler ordering; NO L2 invalidation -> weights stay warm).
__device__ __forceinline__ void grid_barrier(unsigned* slots, unsigned target, int tid){
  __syncthreads();
  asm volatile("" ::: "memory");
  if(tid == 0) st_sys_u(slots + blockIdx.x, target);
  if(tid < 64){
    const unsigned* p0 = slots + tid;
    for(;;){
      unsigned a = ld_sys_u(p0);
      unsigned b = ld_sys_u(p0 + 64);
      unsigned c = ld_sys_u(p0 + 128);
      unsigned d = ld_sys_u(p0 + 192);
      unsigned m = umin2(umin2(a,b), umin2(c,d));
      #pragma unroll
      for(int off=32; off; off>>=1)
        m = umin2(m, (unsigned)__shfl_xor((int)m, off, 64));
      if(m >= target) break;
      __builtin_amdgcn_s_sleep(1);
    }
  }
  __builtin_amdgcn_fence(__ATOMIC_ACQUIRE, "workgroup");  // order only; no cache inv
  __syncthreads();
}

// stage+transpose chunk ch of x[b][t][.] into sbuf[k_local][b], pitch LP
__device__ __forceinline__ void stageA(float* sbuf, const float* __restrict__ x,
                                       int t, int ch, int tid){
  #pragma unroll
  for(int it=0; it<2; ++it){
    int q  = it*NTHR + tid;          // 0..1023
    int b  = q >> 4;
    int k4 = (q & 15) << 2;
    const float4 v = *(const float4*)(x + ((size_t)b*Tlen + t)*Kd + ch*KC + k4);
    sbuf[(k4+0)*LP + b] = v.x;
    sbuf[(k4+1)*LP + b] = v.y;
    sbuf[(k4+2)*LP + b] = v.z;
    sbuf[(k4+3)*LP + b] = v.w;
  }
}

// one k-quad: 24 float4 weight loads (L1-warm) + 96 FMA for 4 cols
__device__ __forceinline__ void quadfma(const float* __restrict__ WiB,
                                        const float* __restrict__ WhB, int kg,
                                        const float* xv, const float* hv,
                                        float* pr, float* pz, float* pni, float* pnh){
  #pragma unroll
  for(int c = 0; c < 4; ++c){
    const float4 a0 = *(const float4*)(WiB + (size_t)c*Kd + kg);
    const float4 a1 = *(const float4*)(WiB + ((size_t)Hd + c)*Kd + kg);
    const float4 a2 = *(const float4*)(WiB + ((size_t)2*Hd + c)*Kd + kg);
    const float4 b0 = *(const float4*)(WhB + (size_t)c*Kd + kg);
    const float4 b1 = *(const float4*)(WhB + ((size_t)Hd + c)*Kd + kg);
    const float4 b2 = *(const float4*)(WhB + ((size_t)2*Hd + c)*Kd + kg);
    pr[c]  = fmaf(xv[0],a0.x, fmaf(xv[1],a0.y, fmaf(xv[2],a0.z, fmaf(xv[3],a0.w, pr[c]))));
    pz[c]  = fmaf(xv[0],a1.x, fmaf(xv[1],a1.y, fmaf(xv[2],a1.z, fmaf(xv[3],a1.w, pz[c]))));
    pni[c] = fmaf(xv[0],a2.x, fmaf(xv[1],a2.y, fmaf(xv[2],a2.z, fmaf(xv[3],a2.w, pni[c]))));
    pr[c]  = fmaf(hv[0],b0.x, fmaf(hv[1],b0.y, fmaf(hv[2],b0.z, fmaf(hv[3],b0.w, pr[c]))));
    pz[c]  = fmaf(hv[0],b1.x, fmaf(hv[1],b1.y, fmaf(hv[2],b1.z, fmaf(hv[3],b1.w, pz[c]))));
    pnh[c] = fmaf(hv[0],b2.x, fmaf(hv[1],b2.y, fmaf(hv[2],b2.z, fmaf(hv[3],b2.w, pnh[c]))));
  }
}

extern "C" __global__ void __launch_bounds__(NTHR, 2)
gru_persist(const float* __restrict__ x,     // [B,T,IN]
            const float* __restrict__ eh,    // [L,B,H]
            const float* __restrict__ Wih,   // [L,3H,IN]
            const float* __restrict__ Whh,   // [L,3H,H]
            const float* __restrict__ bih,   // [L,3H]
            const float* __restrict__ bhh,   // [L,3H]
            float* __restrict__ out,         // [B,T,H] ++ [L,B,H]
            float* __restrict__ ws)
{
  __shared__ float sstage[2*KC*LP];   // 34.3 KB x-staging double buffer
  __shared__ float red[16*8*64];      // 32 KB ksplit-8 reduction buffer

  unsigned* slots = (unsigned*)ws;            // 256 monotonic tick slots
  float* h0T = ws + 256;                      // 2 bufs x [512][64]
  float* h1T = h0T + 2*Kd*Bsz;
  float* htail = out + (size_t)Bsz*Tlen*Hd;

  const int tid  = threadIdx.x;
  const int lane = tid & 63;                                   // batch
  const int wv   = __builtin_amdgcn_readfirstlane(tid >> 6);   // wave id 0..7
  const int cell = blockIdx.x >> 7;                            // 0=layer0, 1=layer1
  const int cb   = blockIdx.x & 127;
  const int col0 = cb * 4;                                     // block's 4 cols
  unsigned bar = 1;

  // ---- init: encoder_h -> parity-1 state bufs, transposed [k][b], coherent ----
  {
    int i = blockIdx.x*NTHR + tid;
    if(i < 2*Kd*Bsz){
      int l = i >> 15, k = (i >> 6) & 511, b = i & 63;
      float v = eh[(size_t)(l*Bsz + b)*Hd + k];
      st_sys((l ? h1T : h0T) + Kd*Bsz + k*Bsz + b, v);
    }
  }
  grid_barrier(slots, bar, tid); bar++;

  const float* WiB = Wih + (size_t)cell*3*Hd*Kd + (size_t)col0*Kd;
  const float* WhB = Whh + (size_t)cell*3*Hd*Kd + (size_t)col0*Kd;
  const int ec   = wv & 3;
  const int ecol = col0 + ec;
  const float bi0 = bih[cell*1536 + 0*Hd + ecol] + bhh[cell*1536 + 0*Hd + ecol];
  const float bi1 = bih[cell*1536 + 1*Hd + ecol] + bhh[cell*1536 + 1*Hd + ecol];
  const float bi2 = bih[cell*1536 + 2*Hd + ecol];
  const float bh2 = bhh[cell*1536 + 2*Hd + ecol];

  // own-column h(t-1) lives in a register (this block is its sole producer)
  float hkeep = eh[((size_t)(cell*Bsz) + lane)*Hd + ecol];

  for(int t = 0; t <= Tlen; ++t){
    const bool active = (cell == 0) ? (t < Tlen) : (t >= 1);
    if(active){
      const int s = (cell == 0) ? t : (t - 1);
      float* hbase = (cell == 0) ? h0T : h1T;
      const float* hprev = hbase + ((s+1)&1)*Kd*Bsz;
      float*       hout  = hbase + (s&1)*Kd*Bsz;
      const float* inT   = h0T + (s&1)*Kd*Bsz;

      float pr[4]={0,0,0,0}, pz[4]={0,0,0,0}, pni[4]={0,0,0,0}, pnh[4]={0,0,0,0};

      if(cell == 0){
        // x via LDS-transpose dbuf (normal cached loads); h via coherent loads,
        // register-prefetched one chunk ahead.
        float hvb[2][8];
        #pragma unroll
        for(int j=0;j<8;++j) hvb[0][j] = ld_sys(hprev + ((wv<<3)+j)*Bsz + lane);
        stageA(sstage, x, t, 0, tid);
        __syncthreads();
        #pragma unroll
        for(int ch = 0; ch < 8; ++ch){
          const float* cur = sstage + (ch&1)*(KC*LP);
          if(ch < 7){
            stageA(sstage + ((ch+1)&1)*(KC*LP), x, t, ch+1, tid);
            #pragma unroll
            for(int j=0;j<8;++j)
              hvb[(ch+1)&1][j] = ld_sys(hprev + (((ch+1)<<6)+(wv<<3)+j)*Bsz + lane);
          }
          float xv[8];
          #pragma unroll
          for(int j=0;j<8;++j) xv[j] = cur[((wv<<3)+j)*LP + lane];
          quadfma(WiB, WhB, (ch<<6)+(wv<<3),     &xv[0], &hvb[ch&1][0], pr,pz,pni,pnh);
          quadfma(WiB, WhB, (ch<<6)+(wv<<3)+4,   &xv[4], &hvb[ch&1][4], pr,pz,pni,pnh);
          __syncthreads();
        }
      } else {
        // both act streams coherent from [k][b]; full unroll -> deep MLP
        #pragma unroll
        for(int jq = 0; jq < 16; ++jq){
          const int kg = (wv<<6) + (jq<<2);
          float xv[4], hv[4];
          #pragma unroll
          for(int u=0;u<4;++u){
            xv[u] = ld_sys(inT   + (size_t)(kg+u)*Bsz + lane);
            hv[u] = ld_sys(hprev + (size_t)(kg+u)*Bsz + lane);
          }
          quadfma(WiB, WhB, kg, xv, hv, pr,pz,pni,pnh);
        }
      }

      // ---- ksplit-8 reduction (disjoint slots per wave; one sync) ----
      #pragma unroll
      for(int c = 0; c < 4; ++c){
        red[(((c<<2)+0)*8 + wv)*64 + lane] = pr[c];
        red[(((c<<2)+1)*8 + wv)*64 + lane] = pz[c];
        red[(((c<<2)+2)*8 + wv)*64 + lane] = pni[c];
        red[(((c<<2)+3)*8 + wv)*64 + lane] = pnh[c];
      }
      __syncthreads();
      if(wv < 4){
        const int c = wv;
        float spr=0.f, spz=0.f, spni=0.f, spnh=0.f;
        #pragma unroll
        for(int w = 0; w < 8; ++w){
          spr  += red[(((c<<2)+0)*8 + w)*64 + lane];
          spz  += red[(((c<<2)+1)*8 + w)*64 + lane];
          spni += red[(((c<<2)+2)*8 + w)*64 + lane];
          spnh += red[(((c<<2)+3)*8 + w)*64 + lane];
        }
        const int col = col0 + c;
        const float r = sigf(spr + bi0);
        const float z = sigf(spz + bi1);
        const float n = tanhx(spni + bi2 + r*(spnh + bh2));
        const float hnew = (1.0f - z)*n + z*hkeep;
        hkeep = hnew;                                   // own col: no reload next tick
        st_sys(hout + col*Bsz + lane, hnew);
        if(cell == 1)
          out[((size_t)lane*Tlen + s)*Hd + col] = hnew;
      }
    }
    grid_barrier(slots, bar, tid); bar++;
  }

  // ---- tail: htail[l][b][c] from parity-1 bufs (coherent reads) ----
  {
    int i = blockIdx.x*NTHR + tid;
    if(i < 2*Kd*Bsz){
      int l = i >> 15, b = (i >> 9) & 63, c = i & 511;
      const float* src = (l ? h1T : h0T) + Kd*Bsz;
      htail[i] = ld_sys(src + c*Bsz + b);
    }
  }
}

extern "C" void kernel_launch(void* const* d_in, const int* in_sizes, int n_in,
                              void* d_out, int out_size, void* d_ws, size_t ws_size,
                              hipStream_t stream) {
  (void)in_sizes; (void)n_in; (void)out_size; (void)ws_size;
  const float* x   = (const float*)d_in[0];
  const float* eh  = (const float*)d_in[1];
  const float* Wih = (const float*)d_in[2];
  const float* Whh = (const float*)d_in[3];
  const float* bih = (const float*)d_in[4];
  const float* bhh = (const float*)d_in[5];
  float* out = (float*)d_out;
  float* ws  = (float*)d_ws;

  hipMemsetAsync(d_ws, 0, 1024, stream);   // zero barrier slots

  void* args[] = {(void*)&x, (void*)&eh, (void*)&Wih, (void*)&Whh,
                  (void*)&bih, (void*)&bhh, (void*)&out, (void*)&ws};
  hipLaunchCooperativeKernel((const void*)gru_persist, dim3(NBLK), dim3(NTHR),
                             args, 0, stream);
}

// Round 5
// 57651.685 us; speedup vs baseline: 1.1849x; 1.1849x over previous
//
#include <hip/hip_runtime.h>

// GRU decoder B=64,T=512,IN=H=512,L=2. Persistent pipelined cooperative grid:
//   blocks [0,128)  = cell A (layer0 @ t),  blocks [128,256) = cell B (layer1 @ t-1)
// 256 blocks x 512 threads (8 waves). Block = 4 cols; wave = 4 cols x K-octant(64).
//
// Round-5: AGENT-scope atomics for h-state (sc1 -> L2-bypass, Infinity-Cache
// coherence point). Round 4's SYSTEM scope bypassed IC too -> 51.8 GB of raw
// HBM traffic. Weights/x use normal cached loads (L1/L2 stay warm; no fences).
// Cell A stages the FULL x_t into LDS once per tick (no per-chunk barriers ->
// no vmcnt(0) drains killing prefetch); XOR-swizzled to avoid 8-way write
// conflicts. Both cells: 16-k chunks, double-buffered register act prefetch.

#define NBLK 256
#define NTHR 512
#define Bsz  64
#define Tlen 512
#define Kd   512
#define Hd   512
#define LPX  65   // LDS pitch for x_t staging

__device__ __forceinline__ float sigf(float v){ return 1.0f/(1.0f+__expf(-v)); }
__device__ __forceinline__ float tanhx(float v){
  float e=__expf(-2.0f*fabsf(v)); float t=(1.0f-e)/(1.0f+e); return v<0.0f?-t:t;
}
__device__ __forceinline__ unsigned umin2(unsigned a, unsigned b){ return a<b?a:b; }

// AGENT-scope relaxed atomics: lower to global_load/store ... sc1 —
// bypass L1/XCD-L2, served/committed at Infinity Cache (device coherence pt).
__device__ __forceinline__ float ld_agt(const float* p){
  return __hip_atomic_load(const_cast<float*>(p), __ATOMIC_RELAXED, __HIP_MEMORY_SCOPE_AGENT);
}
__device__ __forceinline__ void st_agt(float* p, float v){
  __hip_atomic_store(p, v, __ATOMIC_RELAXED, __HIP_MEMORY_SCOPE_AGENT);
}
__device__ __forceinline__ unsigned ld_agt_u(const unsigned* p){
  return __hip_atomic_load(const_cast<unsigned*>(p), __ATOMIC_RELAXED, __HIP_MEMORY_SCOPE_AGENT);
}
__device__ __forceinline__ void st_agt_u(unsigned* p, unsigned v){
  __hip_atomic_store(p, v, __ATOMIC_RELAXED, __HIP_MEMORY_SCOPE_AGENT);
}

// Grid barrier, per-block monotonic slots (no RMW contention).
// Release: __syncthreads drains vmcnt(0) per wave -> all block stores (incl.
// agent h-stores) committed; then slot store. Acquire: wave0 polls slots
// (agent loads can't hit stale caches); __syncthreads blocks hoisting.
__device__ __forceinline__ void grid_barrier(unsigned* slots, unsigned target, int tid){
  __syncthreads();
  if(tid == 0) st_agt_u(slots + blockIdx.x, target);
  if(tid < 64){
    const unsigned* p0 = slots + tid;
    for(;;){
      unsigned a = ld_agt_u(p0);
      unsigned b = ld_agt_u(p0 + 64);
      unsigned c = ld_agt_u(p0 + 128);
      unsigned d = ld_agt_u(p0 + 192);
      unsigned m = umin2(umin2(a,b), umin2(c,d));
      #pragma unroll
      for(int off=32; off; off>>=1)
        m = umin2(m, (unsigned)__shfl_xor((int)m, off, 64));
      if(m >= target) break;
      __builtin_amdgcn_s_sleep(1);
    }
  }
  __builtin_amdgcn_fence(__ATOMIC_ACQUIRE, "workgroup");  // ordering only
  __syncthreads();
}

// stage FULL x_t transposed+swizzled: x[b][t][k] -> sx[k*LPX + (b ^ ((k>>2)&63))]
// coalesced float4 global reads; LDS writes <=2-way conflicted (swizzle).
__device__ __forceinline__ void stage_full(float* sx, const float* __restrict__ x,
                                           int t, int tid){
  #pragma unroll
  for(int it=0; it<16; ++it){
    int q  = it*NTHR + tid;          // 0..8191
    int b  = q >> 7;                 // 0..63
    int k4 = (q & 127) << 2;         // 0..508
    const float4 v = *(const float4*)(x + ((size_t)b*Tlen + t)*Kd + k4);
    sx[(k4+0)*LPX + (b ^ (((k4+0)>>2)&63))] = v.x;
    sx[(k4+1)*LPX + (b ^ (((k4+1)>>2)&63))] = v.y;
    sx[(k4+2)*LPX + (b ^ (((k4+2)>>2)&63))] = v.z;
    sx[(k4+3)*LPX + (b ^ (((k4+3)>>2)&63))] = v.w;
  }
}

// one k-quad: 24 float4 weight loads (L1/L2-warm) + 96 FMA for 4 cols
__device__ __forceinline__ void quadfma(const float* __restrict__ WiB,
                                        const float* __restrict__ WhB, int kg,
                                        const float* xv, const float* hv,
                                        float* pr, float* pz, float* pni, float* pnh){
  #pragma unroll
  for(int c = 0; c < 4; ++c){
    const float4 a0 = *(const float4*)(WiB + (size_t)c*Kd + kg);
    const float4 a1 = *(const float4*)(WiB + ((size_t)Hd + c)*Kd + kg);
    const float4 a2 = *(const float4*)(WiB + ((size_t)2*Hd + c)*Kd + kg);
    const float4 b0 = *(const float4*)(WhB + (size_t)c*Kd + kg);
    const float4 b1 = *(const float4*)(WhB + ((size_t)Hd + c)*Kd + kg);
    const float4 b2 = *(const float4*)(WhB + ((size_t)2*Hd + c)*Kd + kg);
    pr[c]  = fmaf(xv[0],a0.x, fmaf(xv[1],a0.y, fmaf(xv[2],a0.z, fmaf(xv[3],a0.w, pr[c]))));
    pz[c]  = fmaf(xv[0],a1.x, fmaf(xv[1],a1.y, fmaf(xv[2],a1.z, fmaf(xv[3],a1.w, pz[c]))));
    pni[c] = fmaf(xv[0],a2.x, fmaf(xv[1],a2.y, fmaf(xv[2],a2.z, fmaf(xv[3],a2.w, pni[c]))));
    pr[c]  = fmaf(hv[0],b0.x, fmaf(hv[1],b0.y, fmaf(hv[2],b0.z, fmaf(hv[3],b0.w, pr[c]))));
    pz[c]  = fmaf(hv[0],b1.x, fmaf(hv[1],b1.y, fmaf(hv[2],b1.z, fmaf(hv[3],b1.w, pz[c]))));
    pnh[c] = fmaf(hv[0],b2.x, fmaf(hv[1],b2.y, fmaf(hv[2],b2.z, fmaf(hv[3],b2.w, pnh[c]))));
  }
}

extern "C" __global__ void __launch_bounds__(NTHR, 2)
gru_persist(const float* __restrict__ x,     // [B,T,IN]
            const float* __restrict__ eh,    // [L,B,H]
            const float* __restrict__ Wih,   // [L,3H,IN]
            const float* __restrict__ Whh,   // [L,3H,H]
            const float* __restrict__ bih,   // [L,3H]
            const float* __restrict__ bhh,   // [L,3H]
            float* __restrict__ out,         // [B,T,H] ++ [L,B,H]
            float* __restrict__ ws)
{
  __shared__ float sx[Kd * LPX];      // 133 KB: full x_t (cell A); low 32 KB
  float* red = sx;                    // aliased as ksplit-8 reduction buffer

  unsigned* slots = (unsigned*)ws;            // 256 monotonic tick slots
  float* h0T = ws + 256;                      // 2 bufs x [512][64]
  float* h1T = h0T + 2*Kd*Bsz;
  float* htail = out + (size_t)Bsz*Tlen*Hd;

  const int tid  = threadIdx.x;
  const int lane = tid & 63;                                   // batch
  const int wv   = __builtin_amdgcn_readfirstlane(tid >> 6);   // wave id 0..7
  const int cell = blockIdx.x >> 7;                            // 0=layer0, 1=layer1
  const int cb   = blockIdx.x & 127;
  const int col0 = cb * 4;                                     // block's 4 cols
  unsigned bar = 1;

  // ---- init: encoder_h -> parity-1 state bufs, transposed [k][b] ----
  {
    int i = blockIdx.x*NTHR + tid;
    if(i < 2*Kd*Bsz){
      int l = i >> 15, k = (i >> 6) & 511, b = i & 63;
      float v = eh[(size_t)(l*Bsz + b)*Hd + k];
      st_agt((l ? h1T : h0T) + Kd*Bsz + k*Bsz + b, v);
    }
  }
  grid_barrier(slots, bar, tid); bar++;

  const float* WiB = Wih + (size_t)cell*3*Hd*Kd + (size_t)col0*Kd;
  const float* WhB = Whh + (size_t)cell*3*Hd*Kd + (size_t)col0*Kd;
  const int ec   = wv & 3;
  const int ecol = col0 + ec;
  const float bi0 = bih[cell*1536 + 0*Hd + ecol] + bhh[cell*1536 + 0*Hd + ecol];
  const float bi1 = bih[cell*1536 + 1*Hd + ecol] + bhh[cell*1536 + 1*Hd + ecol];
  const float bi2 = bih[cell*1536 + 2*Hd + ecol];
  const float bh2 = bhh[cell*1536 + 2*Hd + ecol];

  // own-column h(t-1) lives in a register (this block is its sole producer)
  float hkeep = eh[((size_t)(cell*Bsz) + lane)*Hd + ecol];

  const int k0 = wv << 6;            // wave's contiguous K-octant

  for(int t = 0; t <= Tlen; ++t){
    const bool active = (cell == 0) ? (t < Tlen) : (t >= 1);
    if(active){
      const int s = (cell == 0) ? t : (t - 1);
      float* hbase = (cell == 0) ? h0T : h1T;
      const float* hprev = hbase + ((s+1)&1)*Kd*Bsz;
      float*       hout  = hbase + (s&1)*Kd*Bsz;
      const float* inT   = h0T + (s&1)*Kd*Bsz;

      float pr[4]={0,0,0,0}, pz[4]={0,0,0,0}, pni[4]={0,0,0,0}, pnh[4]={0,0,0,0};

      if(cell == 0){
        // h prefetch launches first (completes during x staging)
        float hb[2][16];
        #pragma unroll
        for(int j=0;j<16;++j) hb[0][j] = ld_agt(hprev + (size_t)(k0+j)*Bsz + lane);
        stage_full(sx, x, t, tid);
        __syncthreads();
        #pragma unroll
        for(int ch=0; ch<4; ++ch){
          if(ch<3){
            #pragma unroll
            for(int j=0;j<16;++j)
              hb[(ch+1)&1][j] = ld_agt(hprev + (size_t)(k0+((ch+1)<<4)+j)*Bsz + lane);
          }
          float xv[16];
          #pragma unroll
          for(int j=0;j<16;++j){
            const int k = k0 + (ch<<4) + j;
            xv[j] = sx[k*LPX + (lane ^ ((k>>2)&63))];
          }
          #pragma unroll
          for(int q=0;q<4;++q)
            quadfma(WiB, WhB, k0+(ch<<4)+(q<<2), &xv[q<<2], &hb[ch&1][q<<2],
                    pr,pz,pni,pnh);
        }
      } else {
        float xb[2][16], hb[2][16];
        #pragma unroll
        for(int j=0;j<16;++j){
          xb[0][j] = ld_agt(inT   + (size_t)(k0+j)*Bsz + lane);
          hb[0][j] = ld_agt(hprev + (size_t)(k0+j)*Bsz + lane);
        }
        #pragma unroll
        for(int ch=0; ch<4; ++ch){
          if(ch<3){
            #pragma unroll
            for(int j=0;j<16;++j){
              const int kk = k0+((ch+1)<<4)+j;
              xb[(ch+1)&1][j] = ld_agt(inT   + (size_t)kk*Bsz + lane);
              hb[(ch+1)&1][j] = ld_agt(hprev + (size_t)kk*Bsz + lane);
            }
          }
          #pragma unroll
          for(int q=0;q<4;++q)
            quadfma(WiB, WhB, k0+(ch<<4)+(q<<2), &xb[ch&1][q<<2], &hb[ch&1][q<<2],
                    pr,pz,pni,pnh);
        }
      }

      // ---- ksplit-8 reduction via red (aliases sx; sync guards both ways) ----
      __syncthreads();   // cell A: all x-reads done before red overwrites low k
      #pragma unroll
      for(int c = 0; c < 4; ++c){
        red[(((c<<2)+0)*8 + wv)*64 + lane] = pr[c];
        red[(((c<<2)+1)*8 + wv)*64 + lane] = pz[c];
        red[(((c<<2)+2)*8 + wv)*64 + lane] = pni[c];
        red[(((c<<2)+3)*8 + wv)*64 + lane] = pnh[c];
      }
      __syncthreads();
      if(wv < 4){
        const int c = wv;
        float spr=0.f, spz=0.f, spni=0.f, spnh=0.f;
        #pragma unroll
        for(int w = 0; w < 8; ++w){
          spr  += red[(((c<<2)+0)*8 + w)*64 + lane];
          spz  += red[(((c<<2)+1)*8 + w)*64 + lane];
          spni += red[(((c<<2)+2)*8 + w)*64 + lane];
          spnh += red[(((c<<2)+3)*8 + w)*64 + lane];
        }
        const int col = col0 + c;
        const float r = sigf(spr + bi0);
        const float z = sigf(spz + bi1);
        const float n = tanhx(spni + bi2 + r*(spnh + bh2));
        const float hnew = (1.0f - z)*n + z*hkeep;
        hkeep = hnew;                                   // own col: no reload
        st_agt(hout + col*Bsz + lane, hnew);
        if(cell == 1)
          out[((size_t)lane*Tlen + s)*Hd + col] = hnew;
      }
    }
    grid_barrier(slots, bar, tid); bar++;
  }

  // ---- tail: htail[l][b][c] from parity-1 bufs ----
  {
    int i = blockIdx.x*NTHR + tid;
    if(i < 2*Kd*Bsz){
      int l = i >> 15, b = (i >> 9) & 63, c = i & 511;
      const float* src = (l ? h1T : h0T) + Kd*Bsz;
      htail[i] = ld_agt(src + c*Bsz + b);
    }
  }
}

extern "C" void kernel_launch(void* const* d_in, const int* in_sizes, int n_in,
                              void* d_out, int out_size, void* d_ws, size_t ws_size,
                              hipStream_t stream) {
  (void)in_sizes; (void)n_in; (void)out_size; (void)ws_size;
  const float* x   = (const float*)d_in[0];
  const float* eh  = (const float*)d_in[1];
  const float* Wih = (const float*)d_in[2];
  const float* Whh = (const float*)d_in[3];
  const float* bih = (const float*)d_in[4];
  const float* bhh = (const float*)d_in[5];
  float* out = (float*)d_out;
  float* ws  = (float*)d_ws;

  hipMemsetAsync(d_ws, 0, 1024, stream);   // zero barrier slots

  void* args[] = {(void*)&x, (void*)&eh, (void*)&Wih, (void*)&Whh,
                  (void*)&bih, (void*)&bhh, (void*)&out, (void*)&ws};
  hipLaunchCooperativeKernel((const void*)gru_persist, dim3(NBLK), dim3(NTHR),
                             args, 0, stream);
}